// Round 17
// baseline (369.245 us; speedup 1.0000x reference)
//
#include <hip/hip_runtime.h>
#include <hip/hip_bf16.h>

using bf16 = __hip_bfloat16;
typedef __attribute__((ext_vector_type(8))) short bf16x8;
typedef __attribute__((ext_vector_type(4))) float f32x4;

__device__ __forceinline__ float lo2f(unsigned u) { return __uint_as_float(u << 16); }
__device__ __forceinline__ float hi2f(unsigned u) { return __uint_as_float(u & 0xffff0000u); }
__device__ __forceinline__ unsigned pack_bf2(float a, float b) {
    bf16 t0 = __float2bfloat16(a), t1 = __float2bfloat16(b);
    return (unsigned)*(unsigned short*)&t0 | ((unsigned)*(unsigned short*)&t1 << 16);
}

// -------- prep: hist over dst + graph boundaries (fused) --------
__global__ void prep(const int* __restrict__ ei, int E, const int* __restrict__ batch,
                     int N, int G, int* __restrict__ deg, int* __restrict__ gstart)
{
    int i = blockIdx.x * blockDim.x + threadIdx.x;
    if (i < E) atomicAdd(&deg[ei[E + i]], 1);
    if (i < N) {
        int b = batch[i];
        int bp = (i == 0) ? -1 : batch[i - 1];
        for (int q = bp + 1; q <= b; ++q) gstart[q] = i;
        if (i == N - 1)
            for (int q = b + 1; q <= G; ++q) gstart[q] = N;
    }
}

// -------- single-dispatch exclusive scan (published-totals lookback) --------
// Safe: 196 blocks x 4 waves all co-resident on 256 CUs; wait is only on
// lower block ids, which publish totals before their own lookback.
__global__ __launch_bounds__(256)
void scan_lb(const int* __restrict__ deg, int N, int* __restrict__ rowptr,
             float* __restrict__ dinv, int* __restrict__ btot, int* __restrict__ bflag)
{
    __shared__ int sm[256];
    int b = blockIdx.x, t = threadIdx.x;
    int i = b * 256 + t;
    int v = (i < N) ? deg[i] : 0;
    if (i < N) dinv[i] = rsqrtf((float)(v + 1));   // +1 self-loop
    sm[t] = v;
    __syncthreads();
#pragma unroll
    for (int off = 1; off < 256; off <<= 1) {
        int x = (t >= off) ? sm[t - off] : 0;
        __syncthreads();
        sm[t] += x;
        __syncthreads();
    }
    int myinc = sm[t];          // inclusive local scan
    int total = sm[255];
    if (t == 0) {
        btot[b] = total;
        __threadfence();
        atomicExch(&bflag[b], 1);   // publish
    }
    __syncthreads();
    // lookback: thread t (< b) waits for predecessor t and grabs its total
    int c = 0;
    if (t < b) {
        while (atomicAdd(&bflag[t], 0) == 0) {}
        __threadfence();
        c = btot[t];
    }
    sm[t] = c;
    __syncthreads();
#pragma unroll
    for (int off = 1; off < 256; off <<= 1) {
        int x = (t >= off) ? sm[t - off] : 0;
        __syncthreads();
        sm[t] += x;
        __syncthreads();
    }
    int carry = sm[255];        // sum of all predecessor totals
    if (i < N) rowptr[i] = carry + myinc - v;
    if (b == gridDim.x - 1 && t == 255) rowptr[N] = carry + total;
}

// -------- CSR fill (naive: 50000 private write fronts; R11's shared-front
// bucketing regressed 3.5x on 8 non-coherent XCDs) --------
__global__ void fill_col(const int* __restrict__ ei, int E, const int* __restrict__ rowptr,
                         int* __restrict__ cursor, int* __restrict__ col) {
    int e = blockIdx.x * blockDim.x + threadIdx.x;
    if (e >= E) return;
    int s = ei[e];
    int d = ei[E + e];
    int p = atomicAdd(&cursor[d], 1);
    col[rowptr[d] + p] = s;
}

#define LDK 136

// -------- layer-1 GEMM: reads fp32 x directly, bf16 MFMA, fp32 accum --------
__global__ __launch_bounds__(256)
void gemm1_f32(const float* __restrict__ x, const float* __restrict__ W,
               const float* __restrict__ dinv, int N, bf16* __restrict__ g)
{
    __shared__ short Wt[128 * LDK];
    for (int i = threadIdx.x; i < 128 * 128; i += 256) {
        int k = i >> 7, n = i & 127;
        bf16 b = __float2bfloat16(W[i]);   // exact: values bf16-quantized
        Wt[n * LDK + k] = *(short*)&b;
    }
    __syncthreads();

    int wave = threadIdx.x >> 6;
    int lane = threadIdx.x & 63;
    int ln   = lane & 15;
    int quad = lane >> 4;
    int m0 = (blockIdx.x * 4 + wave) * 16;
    if (m0 >= N) return;

    int row = m0 + ln;
    if (row >= N) row = N - 1;
    const float* hrow = x + (size_t)row * 128;

    bf16x8 a[4];
#pragma unroll
    for (int kk = 0; kk < 4; ++kk) {
        float4 f0 = *(const float4*)(hrow + kk * 32 + quad * 8);
        float4 f1 = *(const float4*)(hrow + kk * 32 + quad * 8 + 4);
        float fv[8] = {f0.x, f0.y, f0.z, f0.w, f1.x, f1.y, f1.z, f1.w};
#pragma unroll
        for (int j = 0; j < 8; ++j) {
            bf16 tb = __float2bfloat16(fv[j]);
            ((short*)&a[kk])[j] = *(short*)&tb;
        }
    }

    f32x4 c[8];
#pragma unroll
    for (int nt = 0; nt < 8; ++nt) c[nt] = (f32x4){0.f, 0.f, 0.f, 0.f};
#pragma unroll
    for (int kk = 0; kk < 4; ++kk)
#pragma unroll
        for (int nt = 0; nt < 8; ++nt) {
            bf16x8 b = *(const bf16x8*)&Wt[(nt * 16 + ln) * LDK + kk * 32 + quad * 8];
            c[nt] = __builtin_amdgcn_mfma_f32_16x16x32_bf16(a[kk], b, c[nt], 0, 0, 0);
        }
#pragma unroll
    for (int r = 0; r < 4; ++r) {
        int m = m0 + quad * 4 + r;
        if (m < N) {
            float dv = dinv[m];
#pragma unroll
            for (int nt = 0; nt < 8; ++nt) {
                bf16 val = __float2bfloat16(c[nt][r] * dv);
                ((unsigned short*)g)[(size_t)m * 128 + nt * 16 + ln] = *(unsigned short*)&val;
            }
        }
    }
}

// -------- MFMA GEMM (bf16 h in): g = dinv * (h @ W) --------
__global__ __launch_bounds__(256)
void gemm_mfma(const bf16* __restrict__ hin, const float* __restrict__ W,
               const float* __restrict__ dinv, int N, bf16* __restrict__ g)
{
    __shared__ short Wt[128 * LDK];
    for (int i = threadIdx.x; i < 128 * 128; i += 256) {
        int k = i >> 7, n = i & 127;
        bf16 b = __float2bfloat16(W[i]);
        Wt[n * LDK + k] = *(short*)&b;
    }
    __syncthreads();

    int wave = threadIdx.x >> 6;
    int lane = threadIdx.x & 63;
    int ln   = lane & 15;
    int quad = lane >> 4;
    int m0 = (blockIdx.x * 4 + wave) * 16;
    if (m0 >= N) return;

    int row = m0 + ln;
    if (row >= N) row = N - 1;
    const short* hrow = (const short*)hin + (size_t)row * 128;

    bf16x8 a[4];
#pragma unroll
    for (int kk = 0; kk < 4; ++kk)
        a[kk] = *(const bf16x8*)(hrow + kk * 32 + quad * 8);

    f32x4 c[8];
#pragma unroll
    for (int nt = 0; nt < 8; ++nt) c[nt] = (f32x4){0.f, 0.f, 0.f, 0.f};
#pragma unroll
    for (int kk = 0; kk < 4; ++kk)
#pragma unroll
        for (int nt = 0; nt < 8; ++nt) {
            bf16x8 b = *(const bf16x8*)&Wt[(nt * 16 + ln) * LDK + kk * 32 + quad * 8];
            c[nt] = __builtin_amdgcn_mfma_f32_16x16x32_bf16(a[kk], b, c[nt], 0, 0, 0);
        }
#pragma unroll
    for (int r = 0; r < 4; ++r) {
        int m = m0 + quad * 4 + r;
        if (m < N) {
            float dv = dinv[m];
#pragma unroll
            for (int nt = 0; nt < 8; ++nt) {
                bf16 val = __float2bfloat16(c[nt][r] * dv);
                ((unsigned short*)g)[(size_t)m * 128 + nt * 16 + ln] = *(unsigned short*)&val;
            }
        }
    }
}

// -------- gather: h[v] = [relu](dinv[v]*(g[v] + sum_in g[s]) + bias) --------
__global__ __launch_bounds__(256)
void gather16(const bf16* __restrict__ g, const int* __restrict__ rowptr,
              const int* __restrict__ col, const float* __restrict__ dinv,
              const float* __restrict__ bias, int N, int do_relu, bf16* __restrict__ hout)
{
    int v = blockIdx.x * 4 + (threadIdx.x >> 6);
    if (v >= N) return;
    int lane = threadIdx.x & 63;
    const unsigned* gp = (const unsigned*)g;

    unsigned su = gp[(size_t)v * 64 + lane];
    float s0 = lo2f(su), s1 = hi2f(su);

    int beg = rowptr[v], end = rowptr[v + 1];
    int i = beg;
    for (; i + 8 <= end; i += 8) {
        int cc[8];
#pragma unroll
        for (int j = 0; j < 8; ++j) cc[j] = col[i + j];
        unsigned uu[8];
#pragma unroll
        for (int j = 0; j < 8; ++j) uu[j] = gp[(size_t)cc[j] * 64 + lane];
#pragma unroll
        for (int j = 0; j < 8; ++j) { s0 += lo2f(uu[j]); s1 += hi2f(uu[j]); }
    }
    for (; i + 4 <= end; i += 4) {
        int c0 = col[i], c1 = col[i + 1], c2 = col[i + 2], c3 = col[i + 3];
        unsigned u0 = gp[(size_t)c0 * 64 + lane];
        unsigned u1 = gp[(size_t)c1 * 64 + lane];
        unsigned u2 = gp[(size_t)c2 * 64 + lane];
        unsigned u3 = gp[(size_t)c3 * 64 + lane];
        s0 += lo2f(u0) + lo2f(u1) + lo2f(u2) + lo2f(u3);
        s1 += hi2f(u0) + hi2f(u1) + hi2f(u2) + hi2f(u3);
    }
    for (; i < end; ++i) {
        unsigned u = gp[(size_t)col[i] * 64 + lane];
        s0 += lo2f(u);
        s1 += hi2f(u);
    }
    float dv = dinv[v];
    float2 bb = ((const float2*)bias)[lane];
    float r0 = fmaf(dv, s0, bb.x);
    float r1 = fmaf(dv, s1, bb.y);
    if (do_relu) { r0 = fmaxf(r0, 0.f); r1 = fmaxf(r1, 0.f); }
    ((unsigned*)hout)[(size_t)v * 64 + lane] = pack_bf2(r0, r1);
}

// -------- fused head: sliced pooling + mean-div + mlp1 + relu + mlp2 --------
// 768 threads/block, 1 block/graph. Pooling: 6 groups x 128 feats (chains ~33
// loads, parallel); mlp2 runs on all 12 waves (R16: TLP wins for tiny GEMMs).
__global__ __launch_bounds__(768)
void head_fused(const bf16* __restrict__ h, const int* __restrict__ gstart,
                const float* __restrict__ Wm1, const float* __restrict__ bm1,
                const float* __restrict__ Wm2, const float* __restrict__ bm2,
                float* __restrict__ out)
{
    __shared__ float Part[6][128];
    __shared__ float Ps[128];
    __shared__ float Os[256];
    int gg = blockIdx.x, t = threadIdx.x;
    int s = gstart[gg], e = gstart[gg + 1];
    int len = e - s;
    int grp = t >> 7;        // 0..5
    int f   = t & 127;
    int per = (len + 5) / 6;
    int lo = s + grp * per;
    int hi = min(lo + per, e);
    float acc = 0.f;
    for (int v = lo; v < hi; ++v)
        acc += __bfloat162float(h[(size_t)v * 128 + f]);
    Part[grp][f] = acc;
    __syncthreads();
    if (t < 128) {
        float a = 0.f;
#pragma unroll
        for (int g2 = 0; g2 < 6; ++g2) a += Part[g2][t];
        Ps[t] = a / (float)(len > 0 ? len : 1);
    }
    __syncthreads();
    if (t < 256) {
        float s1 = 0.f;
#pragma unroll 4
        for (int k = 0; k < 128; ++k) s1 = fmaf(Ps[k], Wm1[k * 256 + t], s1);
        Os[t] = fmaxf(s1 + bm1[t], 0.f);
    }
    __syncthreads();
    float s2 = 0.f;
#pragma unroll 4
    for (int k = 0; k < 256; ++k) s2 = fmaf(Os[k], Wm2[k * 768 + t], s2);
    out[(size_t)gg * 768 + t] = s2 + bm2[t];
}

extern "C" void kernel_launch(void* const* d_in, const int* in_sizes, int n_in,
                              void* d_out, int out_size, void* d_ws, size_t ws_size,
                              hipStream_t stream)
{
    const float* x     = (const float*)d_in[0];
    const int*   ei    = (const int*)d_in[1];   // [2,E] int32: src row then dst row
    const int*   batch = (const int*)d_in[2];
    const float *W1 = (const float*)d_in[3],  *bb1 = (const float*)d_in[4];
    const float *W2 = (const float*)d_in[5],  *bb2 = (const float*)d_in[6];
    const float *W3 = (const float*)d_in[7],  *bb3 = (const float*)d_in[8];
    const float *Wm1 = (const float*)d_in[9],  *bm1 = (const float*)d_in[10];
    const float *Wm2 = (const float*)d_in[11], *bm2 = (const float*)d_in[12];

    const int N = in_sizes[2];        // 50000
    const int E = in_sizes[1] / 2;    // 800000
    const int G = out_size / 768;     // 256

    char* wp = (char*)d_ws;
    bf16* bufG   = (bf16*)wp;  wp += (size_t)N * 128 * 2;   // 12.8 MB (g)
    bf16* bufH   = (bf16*)wp;  wp += (size_t)N * 128 * 2;   // 12.8 MB (h)
    int*  col    = (int*)wp;   wp += (size_t)E * 4;         // 3.2 MB
    int*  rowptr = (int*)wp;   wp += (size_t)(N + 1) * 4;
    // contiguous zero region: deg | cursor | bflag (single memset)
    int*  deg    = (int*)wp;   wp += (size_t)N * 4;
    int*  cursor = (int*)wp;   wp += (size_t)N * 4;
    int*  bflag  = (int*)wp;   wp += 256 * 4;
    float* dinv  = (float*)wp; wp += (size_t)N * 4;
    int*  gstart = (int*)wp;   wp += (size_t)(G + 1) * 4;
    int*  btot   = (int*)wp;   wp += 256 * 4;

    hipMemsetAsync(deg, 0, (size_t)N * 4 + (size_t)N * 4 + 256 * 4, stream);

    const int SB = (N + 255) / 256;   // 196 blocks — all co-resident

    prep<<<(E + 255) / 256, 256, 0, stream>>>(ei, E, batch, N, G, deg, gstart);
    scan_lb<<<SB, 256, 0, stream>>>(deg, N, rowptr, dinv, btot, bflag);
    fill_col<<<(E + 255) / 256, 256, 0, stream>>>(ei, E, rowptr, cursor, col);

    const int gemm_grid   = (N + 63) / 64;
    const int gather_grid = (N + 3) / 4;

    // layer 1: x (fp32) -> bufG -> bufH
    gemm1_f32<<<gemm_grid, 256, 0, stream>>>(x, W1, dinv, N, bufG);
    gather16<<<gather_grid, 256, 0, stream>>>(bufG, rowptr, col, dinv, bb1, N, 1, bufH);
    // layer 2
    gemm_mfma<<<gemm_grid, 256, 0, stream>>>(bufH, W2, dinv, N, bufG);
    gather16<<<gather_grid, 256, 0, stream>>>(bufG, rowptr, col, dinv, bb2, N, 1, bufH);
    // layer 3 (no relu)
    gemm_mfma<<<gemm_grid, 256, 0, stream>>>(bufH, W3, dinv, N, bufG);
    gather16<<<gather_grid, 256, 0, stream>>>(bufG, rowptr, col, dinv, bb3, N, 0, bufH);

    // fused pooling + MLP head
    head_fused<<<G, 768, 0, stream>>>(bufH, gstart, Wm1, bm1, Wm2, bm2, (float*)d_out);
}